// Round 8
// baseline (518.764 us; speedup 1.0000x reference)
//
#include <hip/hip_runtime.h>
#include <hip/hip_bf16.h>

#define DEV static __device__ __forceinline__

typedef __attribute__((ext_vector_type(8))) short s16x8;
typedef __attribute__((ext_vector_type(16))) float f32x16;
typedef __attribute__((ext_vector_type(4))) float f32x4;

DEV float bf2f(short s) {
    unsigned u = ((unsigned)(unsigned short)s) << 16;
    union { unsigned u; float f; } c; c.u = u; return c.f;
}
DEV short f2bf(float f) {
    union { float f; unsigned u; } c; c.f = f;
    unsigned u = c.u;
    unsigned r = (u + 0x7FFFu + ((u >> 16) & 1u)) >> 16;
    return (short)r;
}

DEV f32x16 mfma(s16x8 a, s16x8 b, f32x16 c) {
    return __builtin_amdgcn_mfma_f32_32x32x16_bf16(a, b, c, 0, 0, 0);
}
DEV f32x4 mfma16(s16x8 a, s16x8 b, f32x4 c) {
    return __builtin_amdgcn_mfma_f32_16x16x32_bf16(a, b, c, 0, 0, 0);
}

// ------------------------------------------------------- fp32 -> bf16 convert
__global__ void cvt_f32_bf16(const float* __restrict__ src,
                             short* __restrict__ dst, int n) {
    int i = (blockIdx.x * blockDim.x + threadIdx.x) * 4;
    if (i >= n) return;
    float4 v = *(const float4*)(src + i);
    short4 o;
    o.x = f2bf(v.x); o.y = f2bf(v.y); o.z = f2bf(v.z); o.w = f2bf(v.w);
    *(short4*)(dst + i) = o;
}

// ------------------------------------------------------- rotary table
// tab[n][f] = (cos(n*invfreq_f), sin(n*invfreq_f)), n<2048, f<32. 512 KB.
__global__ void rotab(float2* __restrict__ tab) {
    int idx = blockIdx.x * 256 + threadIdx.x;  // 65536 entries
    int n = idx >> 5, f = idx & 31;
    float inv = expf(-0.2878231366f * (float)f);  // 10000^(-f/32)
    float a = (float)n * inv;
    tab[idx] = make_float2(cosf(a), sinf(a));
}

// ------------------------------------------- transpose fp32 (RxC) -> bf16 (CxR)
__global__ void ktransf(const float* __restrict__ src, short* __restrict__ dst,
                        int R, int C) {
    __shared__ __align__(16) short t[32][33];
    int tx = threadIdx.x & 31, ty = threadIdx.x >> 5;  // ty 0..7
    int r0 = blockIdx.y * 32, c0 = blockIdx.x * 32;
    for (int i = 0; i < 32; i += 8)
        t[ty + i][tx] = f2bf(src[(size_t)(r0 + ty + i) * C + c0 + tx]);
    __syncthreads();
    for (int i = 0; i < 32; i += 8)
        dst[(size_t)(c0 + ty + i) * R + r0 + tx] = t[tx][ty + i];
}

// ---------------------------------------------------------------- QKV GEMM
// X (8192 x 512, bf16) @ W (512 x 1536) with W transposed WT (1536 x 512, bf16)
// Epilogue: q scale + rotary (table) -> qws/kws (b,h,n,d); v -> vt (b,h,d,n).
__global__ __launch_bounds__(256) void gemm_qkv(
    const short* __restrict__ X, const short* __restrict__ WT,
    const float2* __restrict__ rtab,
    short* __restrict__ qws, short* __restrict__ kws, short* __restrict__ vt) {
    int wave = threadIdx.x >> 6, lane = threadIdx.x & 63;
    int l31 = lane & 31, lh = lane >> 5;
    int mw = blockIdx.x * 128 + (wave >> 1) * 64;
    int nw = blockIdx.y * 128 + (wave & 1) * 64;
    f32x16 acc[2][2] = {};
    const short* ap = X + (size_t)(mw + l31) * 512 + lh * 8;
    const short* bp = WT + (size_t)(nw + l31) * 512 + lh * 8;
#pragma unroll 4
    for (int k = 0; k < 512; k += 16) {
        s16x8 a0 = *(const s16x8*)(ap + k);
        s16x8 a1 = *(const s16x8*)(ap + 32 * 512 + k);
        s16x8 b0 = *(const s16x8*)(bp + k);
        s16x8 b1 = *(const s16x8*)(bp + 32 * 512 + k);
        acc[0][0] = mfma(a0, b0, acc[0][0]);
        acc[0][1] = mfma(a0, b1, acc[0][1]);
        acc[1][0] = mfma(a1, b0, acc[1][0]);
        acc[1][1] = mfma(a1, b1, acc[1][1]);
    }
#pragma unroll
    for (int ib = 0; ib < 2; ib++)
#pragma unroll
        for (int jb = 0; jb < 2; jb++) {
            int col = nw + jb * 32 + l31;
            int t = col >> 9;          // 0=q 1=k 2=v (uniform across wave)
            int cid = col & 511;
            int h = cid >> 6, d = cid & 63;
#pragma unroll
            for (int r = 0; r < 16; r++) {
                int row = (r & 3) + 8 * (r >> 2) + 4 * lh;
                int gm = mw + ib * 32 + row;
                int b = gm >> 11, n = gm & 2047;
                float v = acc[ib][jb][r];
                if (t == 0) v *= 0.125f;  // DIM_HEAD^-0.5
                if (t < 2) {
                    float pv = __shfl_xor(v, 1);
                    float2 cs = rtab[n * 32 + (d >> 1)];
                    float o = (d & 1) ? (v * cs.x + pv * cs.y)
                                      : (v * cs.x - pv * cs.y);
                    short* dst = (t == 0) ? qws : kws;
                    dst[((size_t)(b * 8 + h) * 2048 + n) * 64 + d] = f2bf(o);
                } else {
                    vt[((size_t)(b * 8 + h) * 64 + d) * 2048 + n] = f2bf(v);
                }
            }
        }
}

// ---------------------------------------------------------------- attention
// Per (b,h): attention over N=2048, D=64, pos_bias (fp32) added.
// No-max softmax (scores+bias bounded ~8.5 -> exp safe in fp32).
//
// Evidence to date: bytes + locality exonerated (R5/R6: FETCH 193->78MB,
// L2-resident, time flat); VALU/LDS exonerated (R7: removed them, slower).
// dur ~= FETCH/BW every round -> fixed-concurrency latency limit (~2.5
// outstanding lines/wave). Root causes attacked here:
//  (1) 2x waves: 16x16x32 MFMA, 16 q-rows/wave -> 4096 1-wave blocks
//      (16/CU target vs 8). Per-wave state halves; mfma chains 2-deep.
//  (2) bias prefetched ONE TILE AHEAD INTO REGISTERS with drain-safe
//      ordering. R5-R7 bug understood: vmcnt is a COUNT, so PV's wait for
//      V (youngest) = vmcnt(0) drained any earlier-issued prefetch every
//      tile. Fix: issue bias(t+1) AFTER V(t); then PV's V-wait is
//      vmcnt(16) and bias stays in flight across exp+PV+K-wait (~700cy).
//  (3) P transpose for PV via 2KB XOR-swizzled LDS (R6-style; 2-way = free).
// 16x16x32 layouts: A row=l15, k=(lane>>4)*8; B col=l15, same k;
// C col=l15, row=(lane>>4)*4+reg (m89-verified).
__global__ __launch_bounds__(64) void attn(
    const short* __restrict__ qws, const short* __restrict__ kws,
    const short* __restrict__ vt, const float* __restrict__ bias,
    short* __restrict__ ows) {
    __shared__ __align__(16) short pls[16 * 64];  // 2 KB, swizzled
    int lane = threadIdx.x;
    int l15 = lane & 15, lh4 = lane >> 4;  // lh4: 0..3
    int bid = blockIdx.x;
    int h = bid & 7;            // XCD-local head (R6 win kept)
    int b = (bid >> 3) & 3;
    int q0 = (bid >> 5) * 16;
    int bh = b * 8 + h;

    // Q fragments: A row = q0+l15, k-slice lh4*8 within each 32-d half
    const short* qp = qws + ((size_t)bh * 2048 + q0 + l15) * 64 + lh4 * 8;
    s16x8 qf[2];
#pragma unroll
    for (int c = 0; c < 2; c++) qf[c] = *(const s16x8*)(qp + 32 * c);

    f32x4 oa[4] = {};          // O[q=lh4*4+r][d=16*j2+l15]
    float lsum[4] = {};        // per-lane partial row sums (q=lh4*4+r)

    const short* kbase = kws + ((size_t)bh * 2048 + l15) * 64 + lh4 * 8;
    const short* vbase = vt + ((size_t)bh * 64 + l15) * 2048 + lh4 * 8;
    // bias row (q0 + lh4*4 + r), col (kb + 16j + l15)
    const float* browp = bias + ((size_t)h * 2048 + q0 + lh4 * 4) * 2048 + l15;

    // prologue: bias tile 0 into registers
    float bcur[16], bnxt[16];
#pragma unroll
    for (int j = 0; j < 4; j++)
#pragma unroll
        for (int r = 0; r < 4; r++)
            bcur[j * 4 + r] = browp[(size_t)r * 2048 + 16 * j];

    for (int kt = 0; kt < 32; kt++) {
        int kb = kt * 64;
        // ---- K fragments (B-op: col=key=kb+16j+l15)
        const short* kp = kbase + (size_t)kb * 64;
        s16x8 kf[4][2];
#pragma unroll
        for (int j = 0; j < 4; j++)
#pragma unroll
            for (int c = 0; c < 2; c++)
                kf[j][c] = *(const s16x8*)(kp + (size_t)(16 * j) * 64 + 32 * c);
        // ---- V fragments (B-op of PV: col=d=16*j2+l15, k=key slice)
        const short* vp = vbase + kb;
        s16x8 vf[2][4];
#pragma unroll
        for (int m = 0; m < 2; m++)
#pragma unroll
            for (int j2 = 0; j2 < 4; j2++)
                vf[m][j2] = *(const s16x8*)(vp + (size_t)(16 * j2) * 2048 + 32 * m);
        // ---- QK^T: S[q=lh4*4+r][key=kb+16j+l15]
        f32x4 s[4] = {};
#pragma unroll
        for (int j = 0; j < 4; j++) {
            s[j] = mfma16(qf[0], kf[j][0], s[j]);
            s[j] = mfma16(qf[1], kf[j][1], s[j]);
        }
        // ---- issue NEXT tile's bias now (after V): PV's V-wait leaves
        // these 16 loads outstanding (vmcnt(16), not 0) -> ~700cy cover.
        if (kt < 31) {
            const float* bnp = browp + (size_t)(kb + 64);
#pragma unroll
            for (int j = 0; j < 4; j++)
#pragma unroll
                for (int r = 0; r < 4; r++)
                    bnxt[j * 4 + r] = bnp[(size_t)r * 2048 + 16 * j];
        }
        __builtin_amdgcn_sched_barrier(0);  // pin issue point (no sinking)
        // ---- exp(S + bias_regs) -> swizzled LDS P[16 q][64 key]
#pragma unroll
        for (int j = 0; j < 4; j++)
#pragma unroll
            for (int r = 0; r < 4; r++) {
                float e = __expf(s[j][r] + bcur[j * 4 + r]);
                lsum[r] += e;
                int q = lh4 * 4 + r;
                pls[q * 64 + ((16 * j + l15) ^ ((q & 7) << 3))] = f2bf(e);
            }
        // ---- P fragments (A-op: row=q=l15, k=key slice 32m+lh4*8)
        s16x8 pa[2];
#pragma unroll
        for (int m = 0; m < 2; m++)
            pa[m] = *(const s16x8*)(
                pls + l15 * 64 + ((32 * m + lh4 * 8) ^ ((l15 & 7) << 3)));
        // ---- PV
#pragma unroll
        for (int j2 = 0; j2 < 4; j2++) {
            oa[j2] = mfma16(pa[0], vf[0][j2], oa[j2]);
            oa[j2] = mfma16(pa[1], vf[1][j2], oa[j2]);
        }
        // rotate bias double-buffer (statically indexed, no scratch)
#pragma unroll
        for (int i = 0; i < 16; i++) bcur[i] = bnxt[i];
    }
    // ---- epilogue: row-sum reduce across l15 (16 lanes), write O
#pragma unroll
    for (int r = 0; r < 4; r++) {
#pragma unroll
        for (int off = 8; off >= 1; off >>= 1)
            lsum[r] += __shfl_xor(lsum[r], off);
        float inv = 1.f / lsum[r];
        int q = lh4 * 4 + r;
        size_t o0 = ((size_t)(b * 2048 + q0 + q) * 8 + h) * 64;
#pragma unroll
        for (int j2 = 0; j2 < 4; j2++)
            ows[o0 + 16 * j2 + l15] = f2bf(oa[j2][r] * inv);
    }
}

// ---------------------------------------------------------------- out GEMM
// O (8192 x 512, bf16) @ W_out (512 x 512) with WT (512 x 512, bf16).
// Output written as FP32 (reference output dtype is float32).
__global__ __launch_bounds__(256) void gemm_out(
    const short* __restrict__ O, const short* __restrict__ WT,
    float* __restrict__ out) {
    int wave = threadIdx.x >> 6, lane = threadIdx.x & 63;
    int l31 = lane & 31, lh = lane >> 5;
    int m0 = blockIdx.x * 128 + (wave >> 1) * 64;
    int n0 = blockIdx.y * 128 + (wave & 1) * 64;
    f32x16 acc[2][2] = {};
    const short* ap = O + (size_t)(m0 + l31) * 512 + lh * 8;
    const short* bp = WT + (size_t)(n0 + l31) * 512 + lh * 8;
#pragma unroll 4
    for (int k = 0; k < 512; k += 16) {
        s16x8 a0 = *(const s16x8*)(ap + k);
        s16x8 a1 = *(const s16x8*)(ap + 32 * 512 + k);
        s16x8 b0 = *(const s16x8*)(bp + k);
        s16x8 b1 = *(const s16x8*)(bp + 32 * 512 + k);
        acc[0][0] = mfma(a0, b0, acc[0][0]);
        acc[0][1] = mfma(a0, b1, acc[0][1]);
        acc[1][0] = mfma(a1, b0, acc[1][0]);
        acc[1][1] = mfma(a1, b1, acc[1][1]);
    }
#pragma unroll
    for (int ib = 0; ib < 2; ib++)
#pragma unroll
        for (int jb = 0; jb < 2; jb++)
#pragma unroll
            for (int r = 0; r < 16; r++) {
                int row = (r & 3) + 8 * (r >> 2) + 4 * lh;
                out[(size_t)(m0 + ib * 32 + row) * 512 + n0 + jb * 32 + l31] =
                    acc[ib][jb][r];
            }
}

// ---------------------------------------------------------------- launch
extern "C" void kernel_launch(void* const* d_in, const int* in_sizes, int n_in,
                              void* d_out, int out_size, void* d_ws,
                              size_t ws_size, hipStream_t stream) {
    const float* x    = (const float*)d_in[0];  // (4,2048,512) fp32
    const float* bias = (const float*)d_in[1];  // (8,2048,2048) fp32
    const float* wqkv = (const float*)d_in[2];  // (512,1536) fp32
    const float* wout = (const float*)d_in[3];  // (512,512) fp32
    float* out = (float*)d_out;                 // (4,2048,512) fp32

    char* ws = (char*)d_ws;
    short* xbf   = (short*)ws;                         // 4M shorts (8 MB)
    short* wqkvT = xbf + 4194304;                      // 1536*512
    short* woutT = wqkvT + 786432;                     // 512*512
    short* qws   = woutT + 262144;                     // 4*8*2048*64
    short* kws   = qws + 4194304;
    short* vt    = kws + 4194304;
    short* ows   = vt + 4194304;
    float2* rtab = (float2*)(ows + 4194304);           // 65536 float2 (512 KB)

    cvt_f32_bf16<<<4096, 256, 0, stream>>>(x, xbf, 4194304);
    rotab<<<256, 256, 0, stream>>>(rtab);
    ktransf<<<dim3(1536 / 32, 512 / 32), 256, 0, stream>>>(wqkv, wqkvT, 512, 1536);
    ktransf<<<dim3(512 / 32, 512 / 32), 256, 0, stream>>>(wout, woutT, 512, 512);
    gemm_qkv<<<dim3(64, 12), 256, 0, stream>>>(xbf, wqkvT, rtab, qws, kws, vt);
    attn<<<4096, 64, 0, stream>>>(qws, kws, vt, bias, ows);
    gemm_out<<<dim3(64, 4), 256, 0, stream>>>(ows, woutT, out);
}